// Round 4
// baseline (510.122 us; speedup 1.0000x reference)
//
#include <hip/hip_runtime.h>
#include <hip/hip_cooperative_groups.h>
#include <math.h>

namespace cg = cooperative_groups;

#define RENDER 256
#define IMG_H 480
#define IMG_W 640
#define NV 2048
#define NF 4096
#define FACE_SLICES 16
#define FACES_PER_SLICE (NF / FACE_SLICES)   // 256
#define N_UNITS (NF / FACES_PER_SLICE * RENDER)  // 4096 tile-slice units
#define NBLOCKS 2048

#define SIGMA_INV 2.0f                    // 1/SIGMA, SIGMA=0.5
#define CAP 13.815510557964274f           // -log(1e-6)
#define LOG2E 1.4426950408889634f
#define LN2 0.6931471805599453f
// 16x16 pixel tile, half-diagonal of pixel centers = 7.5*sqrt(2) = 10.607
// dmin is 1-Lipschitz (min of affine funcs with |grad|<=1):
//   capped everywhere if dmin_center > CAP/2 + rad (+margin)     -> 17.6
//   negligible (<1.6e-8/face) if dmin_center < -(8.99 + rad)     -> -19.6
#define THR_CAP  17.6f
#define THR_SKIP -19.6f

// ws layout:
//   [0, 192KB)       fdata : 4096 faces * 12 floats (3 edges * {A,B,C,pad})
//   [192KB, 448KB)   logp  : 65536 floats
#define WS_FD_OFF    0
#define WS_LOGP_OFF  (192 * 1024)

// ---------------- shared device helpers ----------------------------------

__device__ __forceinline__ void prep_block(const float* __restrict__ dof,
                                           const float* __restrict__ verts,
                                           const int* __restrict__ faces,
                                           const float* __restrict__ Km,
                                           float* __restrict__ fdata,
                                           float* s_buf, int bid) {
    float* sxy = s_buf;   // NV*2 floats = 16 KB
    // --- SE3 exp, redundant per thread (cheap) ---
    float v0 = dof[0], v1 = dof[1], v2 = dof[2];
    float w0 = dof[3], w1 = dof[4], w2 = dof[5];
    float th2 = w0 * w0 + w1 * w1 + w2 * w2;
    float th = sqrtf(th2 + 1e-30f);
    bool small = th < 1e-4f;
    float th_s = small ? 1.0f : th;
    float th2_s = small ? 1.0f : th2;
    float A = small ? (1.0f - th2 / 6.0f) : (sinf(th_s) / th_s);
    float B = small ? (0.5f - th2 / 24.0f) : ((1.0f - cosf(th_s)) / th2_s);
    float C = small ? (1.0f / 6.0f - th2 / 120.0f)
                    : ((th_s - sinf(th_s)) / (th2_s * th_s));
    float Kx[9] = {0.0f, -w2, w1, w2, 0.0f, -w0, -w1, w0, 0.0f};
    float w[3] = {w0, w1, w2};
    float R[9], V[9];
    for (int i = 0; i < 3; i++)
        for (int j = 0; j < 3; j++) {
            float K2 = w[i] * w[j] - (i == j ? th2 : 0.0f);
            float id = (i == j) ? 1.0f : 0.0f;
            R[i * 3 + j] = id + A * Kx[i * 3 + j] + B * K2;
            V[i * 3 + j] = id + B * Kx[i * 3 + j] + C * K2;
        }
    float t0 = V[0] * v0 + V[1] * v1 + V[2] * v2;
    float t1 = V[3] * v0 + V[4] * v1 + V[5] * v2;
    float t2 = V[6] * v0 + V[7] * v1 + V[8] * v2;
    float K00 = Km[0], K01 = Km[1], K02 = Km[2];
    float K10 = Km[3], K11 = Km[4], K12 = Km[5];
    float K20 = Km[6], K21 = Km[7], K22 = Km[8];
    const float scale = 256.0f / 640.0f;

    for (int n = threadIdx.x; n < NV; n += 256) {
        float vx = verts[n * 3], vy = verts[n * 3 + 1], vz = verts[n * 3 + 2];
        float cx = R[0] * vx + R[1] * vy + R[2] * vz + t0;
        float cy = R[3] * vx + R[4] * vy + R[5] * vz + t1;
        float cz = R[6] * vx + R[7] * vy + R[8] * vz + t2;
        float u = K00 * cx + K01 * cy + K02 * cz;
        float v = K10 * cx + K11 * cy + K12 * cz;
        float ww = K20 * cx + K21 * cy + K22 * cz;
        sxy[n * 2]     = u / ww * scale;
        sxy[n * 2 + 1] = v / ww * scale;
    }
    __syncthreads();

    int f = bid * 256 + threadIdx.x;
    int i0 = faces[f * 3], i1 = faces[f * 3 + 1], i2 = faces[f * 3 + 2];
    float x0 = sxy[i0 * 2], y0 = sxy[i0 * 2 + 1];
    float x1 = sxy[i1 * 2], y1 = sxy[i1 * 2 + 1];
    float x2 = sxy[i2 * 2], y2 = sxy[i2 * 2 + 1];
    float ex[3] = {x1 - x0, x2 - x1, x0 - x2};
    float ey[3] = {y1 - y0, y2 - y1, y0 - y2};
    float ax[3] = {x0, x1, x2};
    float ay[3] = {y0, y1, y2};
    float area2 = ex[0] * (-ey[2]) - ey[0] * (-ex[2]);
    float sgn = (area2 >= 0.0f) ? 1.0f : -1.0f;
    float* o = fdata + f * 12;
    for (int k = 0; k < 3; k++) {
        float elen = sqrtf(ex[k] * ex[k] + ey[k] * ey[k]) + 1e-9f;
        float c0 = ex[k] * ay[k] - ey[k] * ax[k];
        float inv = sgn / elen;
        o[k * 4 + 0] = ex[k] * inv;     // A (py coeff)
        o[k * 4 + 1] = -ey[k] * inv;    // B (px coeff)
        o[k * 4 + 2] = -c0 * inv;       // C
        o[k * 4 + 3] = 0.0f;
    }
}

// one tile-slice unit: classify 256 faces, compact survivors to LDS, eval.
__device__ __forceinline__ void raster_unit(const float* __restrict__ fdata,
                                            float* __restrict__ logp,
                                            float* s_buf, int* s_n, int* s_ncap,
                                            int unit) {
    const int tid = threadIdx.x;
    __syncthreads();                 // protect s_buf from previous use
    if (tid == 0) { *s_n = 0; *s_ncap = 0; }
    __syncthreads();

    const int tile = unit >> 4;
    const int slice = unit & 15;
    const int tileX = tile & 15;
    const int tileY = tile >> 4;
    const float cx = tileX * 16 + 8.0f;
    const float cy = tileY * 16 + 8.0f;
    const float4* __restrict__ fd4 = (const float4*)fdata;

    // ---- phase 1: cull + ballot-compact (one face per thread) ----
    {
        int f = slice * FACES_PER_SLICE + tid;
        float4 e0 = fd4[f * 3 + 0];
        float4 e1 = fd4[f * 3 + 1];
        float4 e2 = fd4[f * 3 + 2];
        float d0 = fmaf(e0.y, cx, fmaf(e0.x, cy, e0.z));
        float d1 = fmaf(e1.y, cx, fmaf(e1.x, cy, e1.z));
        float d2 = fmaf(e2.y, cx, fmaf(e2.x, cy, e2.z));
        float dmin = fminf(d0, fminf(d1, d2));
        bool capped = dmin > THR_CAP;
        bool live = (!capped) && (dmin > THR_SKIP);
        unsigned long long mcap = __ballot(capped);
        unsigned long long mliv = __ballot(live);
        int lane = tid & 63;
        int base = 0;
        if (lane == 0) {
            base = atomicAdd(s_n, __popcll(mliv));
            atomicAdd(s_ncap, __popcll(mcap));
        }
        base = __shfl(base, 0, 64);
        if (live) {
            int pos = base + __popcll(mliv & ((1ull << lane) - 1ull));
            float4* dst = (float4*)(s_buf + pos * 12);
            dst[0] = e0; dst[1] = e1; dst[2] = e2;
        }
    }
    __syncthreads();

    // ---- phase 2: evaluate survivors from LDS (broadcast reads) ----
    const int ix = tileX * 16 + (tid & 15);
    const int iy = tileY * 16 + (tid >> 4);
    const float px = (float)ix + 0.5f;
    const float py = (float)iy + 0.5f;

    float acc = -CAP * (float)(*s_ncap);
    const int n = *s_n;
    const float4* sd = (const float4*)s_buf;
    const float ZK = SIGMA_INV * LOG2E;
    #pragma unroll 2
    for (int i = 0; i < n; ++i) {
        float4 e0 = sd[i * 3 + 0];
        float4 e1 = sd[i * 3 + 1];
        float4 e2 = sd[i * 3 + 2];
        float d0 = fmaf(e0.y, px, fmaf(e0.x, py, e0.z));
        float d1 = fmaf(e1.y, px, fmaf(e1.x, py, e1.z));
        float d2 = fmaf(e2.y, px, fmaf(e2.x, py, e2.z));
        float dmin = fminf(d0, fminf(d1, d2));
        // -log1p(-min(sigmoid(2*dmin),1-1e-6)) == min(softplus(2*dmin), CAP)
        float e = __builtin_amdgcn_exp2f(dmin * ZK);
        float sp = __builtin_amdgcn_logf(1.0f + e) * LN2;   // v_log_f32 = log2
        acc -= fminf(sp, CAP);
    }
    atomicAdd(&logp[iy * RENDER + ix], acc);
}

__device__ __forceinline__ void final_block(const float* __restrict__ logp,
                                            const float* __restrict__ mask,
                                            float* __restrict__ out,
                                            float* s_red, int bid) {
    int idx = bid * 256 + threadIdx.x;   // 0 .. 307199
    int r = idx / IMG_W;
    int c = idx - r * IMG_W;
    // jax nearest: in = floor((out+0.5)*256/640) == (2*out+1)/5 exactly
    int ir = (2 * r + 1) / 5;
    int ic = (2 * c + 1) / 5;
    float si = 1.0f - expf(logp[ir * RENDER + ic]);
    out[1 + idx] = si;
    float diff = si - mask[idx];
    float d2 = diff * diff;
    #pragma unroll
    for (int off = 32; off > 0; off >>= 1) d2 += __shfl_down(d2, off, 64);
    int lane = threadIdx.x & 63;
    int wv = threadIdx.x >> 6;
    if (lane == 0) s_red[wv] = d2;
    __syncthreads();
    if (threadIdx.x == 0)
        atomicAdd(out, s_red[0] + s_red[1] + s_red[2] + s_red[3]);
}

// ---------------- single cooperative kernel ------------------------------
__global__ __launch_bounds__(256, 8) void k_all(const float* __restrict__ dof,
                                                const float* __restrict__ verts,
                                                const int* __restrict__ faces,
                                                const float* __restrict__ Km,
                                                const float* __restrict__ mask,
                                                float* __restrict__ fdata,
                                                float* __restrict__ logp,
                                                float* __restrict__ out) {
    __shared__ float s_buf[NV * 2];   // 16 KB: sxy in prep, survivors in raster
    __shared__ int s_n, s_ncap;
    __shared__ float s_red[4];
    cg::grid_group grid = cg::this_grid();
    const int bid = blockIdx.x;

    // ---- phase A: prep ----
    if (bid < 16) {
        prep_block(dof, verts, faces, Km, fdata, s_buf, bid);
    } else if (bid < 272) {
        logp[(bid - 16) * 256 + threadIdx.x] = 0.0f;
        if (bid == 16 && threadIdx.x == 0) out[0] = 0.0f;
    }
    grid.sync();

    // ---- phase B: raster, 2 hashed units per block ----
    raster_unit(fdata, logp, s_buf, &s_n, &s_ncap, ((2 * bid + 0) * 2053) & (N_UNITS - 1));
    raster_unit(fdata, logp, s_buf, &s_n, &s_ncap, ((2 * bid + 1) * 2053) & (N_UNITS - 1));
    grid.sync();

    // ---- phase C: resize + loss ----
    if (bid < (IMG_H * IMG_W) / 256)
        final_block(logp, mask, out, s_red, bid);
}

// ---------------- fallback (non-cooperative) path ------------------------
__global__ __launch_bounds__(256) void k_prep_fb(const float* __restrict__ dof,
                                                 const float* __restrict__ verts,
                                                 const int* __restrict__ faces,
                                                 const float* __restrict__ Km,
                                                 float* __restrict__ fdata,
                                                 float* __restrict__ logp,
                                                 float* __restrict__ out) {
    __shared__ float s_buf[NV * 2];
    if (blockIdx.x >= 16) {
        logp[(blockIdx.x - 16) * 256 + threadIdx.x] = 0.0f;
        if (blockIdx.x == 16 && threadIdx.x == 0) out[0] = 0.0f;
        return;
    }
    prep_block(dof, verts, faces, Km, fdata, s_buf, blockIdx.x);
}

__global__ __launch_bounds__(256) void k_raster_fb(const float* __restrict__ fdata,
                                                   float* __restrict__ logp) {
    __shared__ float s_buf[FACES_PER_SLICE * 12];
    __shared__ int s_n, s_ncap;
    raster_unit(fdata, logp, s_buf, &s_n, &s_ncap, (blockIdx.x * 2053) & (N_UNITS - 1));
}

__global__ __launch_bounds__(256) void k_final_fb(const float* __restrict__ logp,
                                                  const float* __restrict__ mask,
                                                  float* __restrict__ out) {
    __shared__ float s_red[4];
    final_block(logp, mask, out, s_red, blockIdx.x);
}

extern "C" void kernel_launch(void* const* d_in, const int* in_sizes, int n_in,
                              void* d_out, int out_size, void* d_ws, size_t ws_size,
                              hipStream_t stream) {
    const float* dof   = (const float*)d_in[0];
    const float* verts = (const float*)d_in[1];
    const int*   faces = (const int*)d_in[2];
    const float* Km    = (const float*)d_in[3];
    const float* mask  = (const float*)d_in[4];
    float* out = (float*)d_out;

    char* ws = (char*)d_ws;
    float* fdata = (float*)(ws + WS_FD_OFF);
    float* logp  = (float*)(ws + WS_LOGP_OFF);

    void* args[] = {(void*)&dof, (void*)&verts, (void*)&faces, (void*)&Km,
                    (void*)&mask, (void*)&fdata, (void*)&logp, (void*)&out};
    hipError_t err = hipLaunchCooperativeKernel((void*)k_all, dim3(NBLOCKS),
                                                dim3(256), args, 0, stream);
    if (err != hipSuccess) {
        // fallback: 3 regular kernels
        k_prep_fb<<<272, 256, 0, stream>>>(dof, verts, faces, Km, fdata, logp, out);
        k_raster_fb<<<N_UNITS, 256, 0, stream>>>(fdata, logp);
        k_final_fb<<<(IMG_H * IMG_W) / 256, 256, 0, stream>>>(logp, mask, out);
    }
}

// Round 5
// 105.337 us; speedup vs baseline: 4.8427x; 4.8427x over previous
//
#include <hip/hip_runtime.h>
#include <math.h>

#define RENDER 256
#define IMG_H 480
#define IMG_W 640
#define NV 2048
#define NF 4096
#define FACE_SLICES 32
#define FACES_PER_SLICE (NF / FACE_SLICES)       // 128
#define N_UNITS (256 * FACE_SLICES)              // 8192 tile-slice units

#define SIGMA_INV 2.0f                           // 1/SIGMA, SIGMA=0.5
#define CAP 13.815510557964274f                  // -log(1e-6)
#define LOG2E 1.4426950408889634f
#define LN2 0.6931471805599453f
#define ZK 2.8853900817779268f                   // SIGMA_INV * LOG2E (coeff prescale)
#define CAP2 19.931568569324174f                 // CAP * LOG2E
// 16x16 pixel tile, half-diagonal of pixel centers = 7.5*sqrt(2) = 10.607.
// dmin is 1-Lipschitz in UNSCALED units; thresholds below are the round-3
// values (17.6 / -19.6) multiplied by ZK since coefficients are prescaled.
#define THR_CAP2  50.8f
#define THR_SKIP2 -56.6f

// ws layout:
//   [0, 192KB)       fdata : 4096 faces * 12 floats (3 edges * {A,B,C,pad})
//   [192KB, 448KB)   logp  : 65536 floats
#define WS_FD_OFF    0
#define WS_LOGP_OFF  (192 * 1024)

// ---------------- kernel 1: fused setup ----------------------------------
// blocks 0..15   : SE3 exp (redundant per thread) + project all verts into
//                  LDS (redundant per block) + per-face edge coefficients
//                  (prescaled by ZK)
// blocks 16..271 : zero logp; block 16 thread 0 zeros out[0]
__global__ __launch_bounds__(256) void k_prep(const float* __restrict__ dof,
                                              const float* __restrict__ verts,
                                              const int* __restrict__ faces,
                                              const float* __restrict__ Km,
                                              float* __restrict__ fdata,
                                              float* __restrict__ logp,
                                              float* __restrict__ out) {
    if (blockIdx.x >= 16) {
        logp[(blockIdx.x - 16) * 256 + threadIdx.x] = 0.0f;
        if (blockIdx.x == 16 && threadIdx.x == 0) out[0] = 0.0f;
        return;
    }

    __shared__ float sxy[NV * 2];   // 16 KB projected verts

    float v0 = dof[0], v1 = dof[1], v2 = dof[2];
    float w0 = dof[3], w1 = dof[4], w2 = dof[5];
    float th2 = w0 * w0 + w1 * w1 + w2 * w2;
    float th = sqrtf(th2 + 1e-30f);
    bool small = th < 1e-4f;
    float th_s = small ? 1.0f : th;
    float th2_s = small ? 1.0f : th2;
    float A = small ? (1.0f - th2 / 6.0f) : (sinf(th_s) / th_s);
    float B = small ? (0.5f - th2 / 24.0f) : ((1.0f - cosf(th_s)) / th2_s);
    float C = small ? (1.0f / 6.0f - th2 / 120.0f)
                    : ((th_s - sinf(th_s)) / (th2_s * th_s));
    float Kx[9] = {0.0f, -w2, w1, w2, 0.0f, -w0, -w1, w0, 0.0f};
    float w[3] = {w0, w1, w2};
    float R[9], V[9];
    for (int i = 0; i < 3; i++)
        for (int j = 0; j < 3; j++) {
            float K2 = w[i] * w[j] - (i == j ? th2 : 0.0f);
            float id = (i == j) ? 1.0f : 0.0f;
            R[i * 3 + j] = id + A * Kx[i * 3 + j] + B * K2;
            V[i * 3 + j] = id + B * Kx[i * 3 + j] + C * K2;
        }
    float t0 = V[0] * v0 + V[1] * v1 + V[2] * v2;
    float t1 = V[3] * v0 + V[4] * v1 + V[5] * v2;
    float t2 = V[6] * v0 + V[7] * v1 + V[8] * v2;
    float K00 = Km[0], K01 = Km[1], K02 = Km[2];
    float K10 = Km[3], K11 = Km[4], K12 = Km[5];
    float K20 = Km[6], K21 = Km[7], K22 = Km[8];
    const float scale = 256.0f / 640.0f;

    for (int n = threadIdx.x; n < NV; n += 256) {
        float vx = verts[n * 3], vy = verts[n * 3 + 1], vz = verts[n * 3 + 2];
        float cx = R[0] * vx + R[1] * vy + R[2] * vz + t0;
        float cy = R[3] * vx + R[4] * vy + R[5] * vz + t1;
        float cz = R[6] * vx + R[7] * vy + R[8] * vz + t2;
        float u = K00 * cx + K01 * cy + K02 * cz;
        float v = K10 * cx + K11 * cy + K12 * cz;
        float ww = K20 * cx + K21 * cy + K22 * cz;
        sxy[n * 2]     = u / ww * scale;
        sxy[n * 2 + 1] = v / ww * scale;
    }
    __syncthreads();

    int f = blockIdx.x * 256 + threadIdx.x;
    int i0 = faces[f * 3], i1 = faces[f * 3 + 1], i2 = faces[f * 3 + 2];
    float x0 = sxy[i0 * 2], y0 = sxy[i0 * 2 + 1];
    float x1 = sxy[i1 * 2], y1 = sxy[i1 * 2 + 1];
    float x2 = sxy[i2 * 2], y2 = sxy[i2 * 2 + 1];
    float ex[3] = {x1 - x0, x2 - x1, x0 - x2};
    float ey[3] = {y1 - y0, y2 - y1, y0 - y2};
    float ax[3] = {x0, x1, x2};
    float ay[3] = {y0, y1, y2};
    float area2 = ex[0] * (-ey[2]) - ey[0] * (-ex[2]);
    float sgn = (area2 >= 0.0f) ? 1.0f : -1.0f;
    float* o = fdata + f * 12;
    for (int k = 0; k < 3; k++) {
        float elen = sqrtf(ex[k] * ex[k] + ey[k] * ey[k]) + 1e-9f;
        float c0 = ex[k] * ay[k] - ey[k] * ax[k];
        float inv = sgn / elen * ZK;       // prescale into log2 domain
        o[k * 4 + 0] = ex[k] * inv;        // A (py coeff)
        o[k * 4 + 1] = -ey[k] * inv;       // B (px coeff)
        o[k * 4 + 2] = -c0 * inv;          // C
        o[k * 4 + 3] = 0.0f;
    }
}

// ---------------- kernel 2: tiled + culled soft rasterization ------------
// 8192 blocks; block -> unit via odd-multiplier hash (bijection mod 8192)
// so heavy (central) tiles scatter across CUs. unit = tile*32 + slice.
// Phase 1: threads 0..127 classify the slice's 128 faces at tile center,
//          ballot-compact survivor coefficients into LDS.
// Phase 2: 256 threads = 16x16 pixels evaluate the survivor list
//          (software-pipelined broadcast LDS reads).
__global__ __launch_bounds__(256) void k_raster(const float* __restrict__ fdata,
                                                float* __restrict__ logp) {
    __shared__ float s_data[(FACES_PER_SLICE + 1) * 12];   // +1 slot for prefetch
    __shared__ int s_n;
    __shared__ int s_ncap;
    const int tid = threadIdx.x;
    if (tid == 0) { s_n = 0; s_ncap = 0; }
    __syncthreads();

    const int unit = (blockIdx.x * 2053) & (N_UNITS - 1);
    const int tile = unit >> 5;
    const int slice = unit & 31;
    const int tileX = tile & 15;
    const int tileY = tile >> 4;
    const float cx = tileX * 16 + 8.0f;
    const float cy = tileY * 16 + 8.0f;
    const float4* __restrict__ fd4 = (const float4*)fdata;

    // ---- phase 1: cull + ballot-compact ----
    if (tid < FACES_PER_SLICE) {
        int f = slice * FACES_PER_SLICE + tid;
        float4 e0 = fd4[f * 3 + 0];
        float4 e1 = fd4[f * 3 + 1];
        float4 e2 = fd4[f * 3 + 2];
        float d0 = fmaf(e0.y, cx, fmaf(e0.x, cy, e0.z));
        float d1 = fmaf(e1.y, cx, fmaf(e1.x, cy, e1.z));
        float d2 = fmaf(e2.y, cx, fmaf(e2.x, cy, e2.z));
        float dmin = fminf(d0, fminf(d1, d2));
        bool capped = dmin > THR_CAP2;
        bool live = (!capped) && (dmin > THR_SKIP2);
        unsigned long long mcap = __ballot(capped);
        unsigned long long mliv = __ballot(live);
        int lane = tid & 63;
        int base = 0;
        if (lane == 0) {
            base = atomicAdd(&s_n, __popcll(mliv));
            atomicAdd(&s_ncap, __popcll(mcap));
        }
        base = __shfl(base, 0, 64);
        if (live) {
            int pos = base + __popcll(mliv & ((1ull << lane) - 1ull));
            float4* dst = (float4*)(s_data + pos * 12);
            dst[0] = e0; dst[1] = e1; dst[2] = e2;
        }
    }
    __syncthreads();

    const int n = s_n;
    const int ncap = s_ncap;
    if (n == 0 && ncap == 0) return;     // empty unit: no contribution

    // ---- phase 2: evaluate survivors (pipelined LDS broadcast) ----
    const int ix = tileX * 16 + (tid & 15);
    const int iy = tileY * 16 + (tid >> 4);
    const float px = (float)ix + 0.5f;
    const float py = (float)iy + 0.5f;

    float acc2 = -CAP2 * (float)ncap;
    const float4* sd = (const float4*)s_data;
    float4 c0 = sd[0], c1 = sd[1], c2 = sd[2];
    for (int i = 0; i < n; ++i) {
        float4 n0 = sd[(i + 1) * 3 + 0];   // padded slot makes i==n-1 safe
        float4 n1 = sd[(i + 1) * 3 + 1];
        float4 n2 = sd[(i + 1) * 3 + 2];
        float d0 = fmaf(c0.y, px, fmaf(c0.x, py, c0.z));
        float d1 = fmaf(c1.y, px, fmaf(c1.x, py, c1.z));
        float d2 = fmaf(c2.y, px, fmaf(c2.x, py, c2.z));
        float z = fminf(d0, fminf(d1, d2));          // 2*log2e*dmin
        float e = __builtin_amdgcn_exp2f(z);
        float sp2 = __builtin_amdgcn_logf(1.0f + e); // log2(1+2^z) = softplus*log2e
        acc2 -= fminf(sp2, CAP2);
        c0 = n0; c1 = n1; c2 = n2;
    }
    atomicAdd(&logp[iy * RENDER + ix], acc2 * LN2);
}

// ---------------- kernel 3: resize-nearest + crop + SSE loss -------------
__global__ __launch_bounds__(256) void k_final(const float* __restrict__ logp,
                                               const float* __restrict__ mask,
                                               float* __restrict__ out) {
    int idx = blockIdx.x * 256 + threadIdx.x;   // 0 .. 307199
    int r = idx / IMG_W;
    int c = idx - r * IMG_W;
    // jax nearest: in = floor((out+0.5)*256/640) == (2*out+1)/5 exactly
    int ir = (2 * r + 1) / 5;
    int ic = (2 * c + 1) / 5;
    float si = 1.0f - expf(logp[ir * RENDER + ic]);
    out[1 + idx] = si;
    float diff = si - mask[idx];
    float d2 = diff * diff;
    #pragma unroll
    for (int off = 32; off > 0; off >>= 1) d2 += __shfl_down(d2, off, 64);
    __shared__ float sred[4];
    int lane = threadIdx.x & 63;
    int wv = threadIdx.x >> 6;
    if (lane == 0) sred[wv] = d2;
    __syncthreads();
    if (threadIdx.x == 0)
        atomicAdd(out, sred[0] + sred[1] + sred[2] + sred[3]);
}

extern "C" void kernel_launch(void* const* d_in, const int* in_sizes, int n_in,
                              void* d_out, int out_size, void* d_ws, size_t ws_size,
                              hipStream_t stream) {
    const float* dof   = (const float*)d_in[0];
    const float* verts = (const float*)d_in[1];
    const int*   faces = (const int*)d_in[2];
    const float* Km    = (const float*)d_in[3];
    const float* mask  = (const float*)d_in[4];
    float* out = (float*)d_out;

    char* ws = (char*)d_ws;
    float* fdata = (float*)(ws + WS_FD_OFF);
    float* logp  = (float*)(ws + WS_LOGP_OFF);

    k_prep<<<272, 256, 0, stream>>>(dof, verts, faces, Km, fdata, logp, out);
    k_raster<<<N_UNITS, 256, 0, stream>>>(fdata, logp);
    k_final<<<(IMG_H * IMG_W) / 256, 256, 0, stream>>>(logp, mask, out);
}